// Round 2
// baseline (572.888 us; speedup 1.0000x reference)
//
#include <hip/hip_runtime.h>
#include <math.h>

typedef unsigned short u16;
typedef unsigned int u32;
typedef __attribute__((ext_vector_type(8))) short bf16x8;
typedef __attribute__((ext_vector_type(4))) float f32x4;

__device__ __forceinline__ u16 f2b(float f){
  u32 u = __float_as_uint(f);
  u32 r = (u + 0x7FFFu + ((u >> 16) & 1u)) >> 16;
  return (u16)r;
}
__device__ __forceinline__ float b2f(u16 h){ return __uint_as_float(((u32)h) << 16); }

__device__ __forceinline__ void gll16(const void* g, void* l){
  __builtin_amdgcn_global_load_lds((const __attribute__((address_space(1))) void*)g,
                                   (__attribute__((address_space(3))) void*)l, 16, 0, 0);
}

// ---------------- pack kernels ----------------
__global__ __launch_bounds__(256) void pack_x(const float* __restrict__ in, u16* __restrict__ out){
  const int i = blockIdx.x * 256 + threadIdx.x;   // 4096*256 = 1,048,576 float4s exactly
  const float4 v = ((const float4*)in)[i];
  ushort4 o; o.x = f2b(v.x); o.y = f2b(v.y); o.z = f2b(v.z); o.w = f2b(v.w);
  ((ushort4*)out)[i] = o;
}

// in: f32 [1024 k][1024 n] row-major. out: bf16 [1024 n][1024 k] (transposed)
__global__ __launch_bounds__(256) void pack_wT(const float* __restrict__ in, u16* __restrict__ out){
  const int idx = blockIdx.x * 256 + threadIdx.x; // 1,048,576 exactly
  const int n = idx >> 10, k = idx & 1023;
  out[idx] = f2b(in[(k << 10) + n]);
}

// ---------------- 128x128 bf16 GEMM, B^T layout (m97 structure) ----------------
// EPI 0: QKV split epilogue. EPI 1: bias+gelu -> o0 (bf16). EPI 3: bias+residual -> fo (f32 d_out).
template<int EPI>
__global__ __launch_bounds__(256) void gemm_bt(
    const u16* __restrict__ A, const u16* __restrict__ Bt, int K,
    const float* __restrict__ bias0, const float* __restrict__ bias1, const float* __restrict__ bias2,
    u16* __restrict__ o0, u16* __restrict__ o1, u16* __restrict__ o2,
    const u16* __restrict__ res, float* __restrict__ fo)
{
  __shared__ __align__(16) u16 As[128 * 32];
  __shared__ __align__(16) u16 Bs[128 * 32];
  const int bm = blockIdx.x, bn = blockIdx.y;
  const int tid = threadIdx.x, w = tid >> 6, l = tid & 63;
  const int wm = (w >> 1) * 64, wn = (w & 1) * 64;
  const u16* Ab = A + (size_t)bm * 128 * K;
  const u16* Bb = Bt + (size_t)bn * 128 * K;
  const int srow = w * 16 + (l >> 2);
  const int scol = (l & 3) * 8;
  f32x4 acc[4][4];
  #pragma unroll
  for (int m = 0; m < 4; ++m)
    #pragma unroll
    for (int n = 0; n < 4; ++n) acc[m][n] = (f32x4){0.f, 0.f, 0.f, 0.f};
  const int nk = K >> 5;
  for (int kt = 0; kt < nk; ++kt){
    const int k0 = kt << 5;
    #pragma unroll
    for (int j = 0; j < 2; ++j){
      gll16(Ab + (size_t)(j * 64 + srow) * K + (k0 + scol), (char*)As + j * 4096 + w * 1024);
      gll16(Bb + (size_t)(j * 64 + srow) * K + (k0 + scol), (char*)Bs + j * 4096 + w * 1024);
    }
    __syncthreads();
    bf16x8 af[4], bfr[4];
    #pragma unroll
    for (int m = 0; m < 4; ++m) af[m]  = *(const bf16x8*)&As[(wm + m * 16 + (l & 15)) * 32 + (l >> 4) * 8];
    #pragma unroll
    for (int n = 0; n < 4; ++n) bfr[n] = *(const bf16x8*)&Bs[(wn + n * 16 + (l & 15)) * 32 + (l >> 4) * 8];
    #pragma unroll
    for (int m = 0; m < 4; ++m)
      #pragma unroll
      for (int n = 0; n < 4; ++n)
        acc[m][n] = __builtin_amdgcn_mfma_f32_16x16x32_bf16(af[m], bfr[n], acc[m][n], 0, 0, 0);
    __syncthreads();
  }
  #pragma unroll
  for (int m = 0; m < 4; ++m){
    #pragma unroll
    for (int n = 0; n < 4; ++n){
      const int row0 = bm * 128 + wm + m * 16 + ((l >> 4) << 2);
      const int col  = bn * 128 + wn + n * 16 + (l & 15);
      if (EPI == 0){
        const int sec = col >> 10, cw = col & 1023, hh = cw >> 6, d = cw & 63;
        const float bias = (sec == 0 ? bias0 : (sec == 1 ? bias1 : bias2))[cw];
        #pragma unroll
        for (int r = 0; r < 4; ++r){
          const int rr = row0 + r, bi = rr >> 11, seq = rr & 2047;
          const float v = acc[m][n][r] + bias;
          if (sec == 0)      o0[(((size_t)bi * 16 + hh) * 2048 + seq) * 64 + d] = f2b(v);
          else if (sec == 1) o1[(((size_t)bi * 16 + hh) * 2048 + seq) * 64 + d] = f2b(v);
          else               o2[(((size_t)bi * 16 + hh) * 64 + d) * 2048 + seq] = f2b(v);
        }
      } else if (EPI == 1){
        const float bias = bias0[col];
        #pragma unroll
        for (int r = 0; r < 4; ++r){
          const float v = acc[m][n][r] + bias;
          const float gv = 0.5f * v * (1.0f + erff(v * 0.70710678118654752f));
          o0[(size_t)(row0 + r) * 1024 + col] = f2b(gv);
        }
      } else {  // EPI == 3: bias + bf16 residual -> float32 output
        const float bias = bias0[col];
        #pragma unroll
        for (int r = 0; r < 4; ++r){
          const float v = acc[m][n][r] + bias + b2f(res[(size_t)(row0 + r) * 1024 + col]);
          fo[(size_t)(row0 + r) * 1024 + col] = v;
        }
      }
    }
  }
}

// ---------------- attention pass 1: per-row max m and denom l ----------------
__global__ __launch_bounds__(256) void attn_ml(const u16* __restrict__ Qb, const u16* __restrict__ Kb,
                                               float* __restrict__ ml){
  const int qt = blockIdx.x & 31, bh = blockIdx.x >> 5;
  const int tid = threadIdx.x, w = tid >> 6, l = tid & 63;
  const u16* Qh = Qb + (size_t)bh * (2048 * 64);
  const u16* Kh = Kb + (size_t)bh * (2048 * 64);
  const int q0 = qt * 64 + w * 16;
  const bf16x8 qa0 = *(const bf16x8*)&Qh[(size_t)(q0 + (l & 15)) * 64 + (l >> 4) * 8];
  const bf16x8 qa1 = *(const bf16x8*)&Qh[(size_t)(q0 + (l & 15)) * 64 + 32 + (l >> 4) * 8];
  float mrun[4] = {-1e30f, -1e30f, -1e30f, -1e30f};
  float lrun[4] = {0.f, 0.f, 0.f, 0.f};
  for (int kt = 0; kt < 32; ++kt){
    f32x4 s[4];
    #pragma unroll
    for (int n = 0; n < 4; ++n){
      s[n] = (f32x4){0.f, 0.f, 0.f, 0.f};
      const int krow = kt * 64 + n * 16 + (l & 15);
      const bf16x8 k0 = *(const bf16x8*)&Kh[(size_t)krow * 64 + (l >> 4) * 8];
      const bf16x8 k1 = *(const bf16x8*)&Kh[(size_t)krow * 64 + 32 + (l >> 4) * 8];
      s[n] = __builtin_amdgcn_mfma_f32_16x16x32_bf16(qa0, k0, s[n], 0, 0, 0);
      s[n] = __builtin_amdgcn_mfma_f32_16x16x32_bf16(qa1, k1, s[n], 0, 0, 0);
    }
    float mx[4], es[4];
    #pragma unroll
    for (int r = 0; r < 4; ++r)
      mx[r] = fmaxf(fmaxf(s[0][r], s[1][r]), fmaxf(s[2][r], s[3][r])) * 0.125f;
    #pragma unroll
    for (int off = 1; off < 16; off <<= 1)
      #pragma unroll
      for (int r = 0; r < 4; ++r) mx[r] = fmaxf(mx[r], __shfl_xor(mx[r], off));
    #pragma unroll
    for (int r = 0; r < 4; ++r){
      const float mnew = fmaxf(mrun[r], mx[r]);
      es[r] = __expf(s[0][r] * 0.125f - mnew) + __expf(s[1][r] * 0.125f - mnew)
            + __expf(s[2][r] * 0.125f - mnew) + __expf(s[3][r] * 0.125f - mnew);
      lrun[r] = lrun[r] * __expf(mrun[r] - mnew);
      mrun[r] = mnew;
    }
    #pragma unroll
    for (int off = 1; off < 16; off <<= 1)
      #pragma unroll
      for (int r = 0; r < 4; ++r) es[r] += __shfl_xor(es[r], off);
    #pragma unroll
    for (int r = 0; r < 4; ++r) lrun[r] += es[r];
  }
  if ((l & 15) == 0){
    #pragma unroll
    for (int r = 0; r < 4; ++r){
      const int q = q0 + (l >> 4) * 4 + r;
      float2 st; st.x = mrun[r]; st.y = lrun[r];
      ((float2*)ml)[(size_t)bh * 2048 + q] = st;
    }
  }
}

// ---------------- attention pass 2a: normalized P (bf16) for one (b, q-chunk) ----------------
__global__ __launch_bounds__(256) void scores_p(const u16* __restrict__ Qb, const u16* __restrict__ Kb,
    const float* __restrict__ ml, u16* __restrict__ P, int b, int qbase, int QC)
{
  const int h = blockIdx.x, qt = blockIdx.y;
  const int bh = b * 16 + h;
  const int tid = threadIdx.x, w = tid >> 6, l = tid & 63;
  const u16* Qh = Qb + (size_t)bh * (2048 * 64);
  const u16* Kh = Kb + (size_t)bh * (2048 * 64);
  const int q0 = qbase + qt * 64 + w * 16;
  const bf16x8 qa0 = *(const bf16x8*)&Qh[(size_t)(q0 + (l & 15)) * 64 + (l >> 4) * 8];
  const bf16x8 qa1 = *(const bf16x8*)&Qh[(size_t)(q0 + (l & 15)) * 64 + 32 + (l >> 4) * 8];
  float m_[4], il[4];
  #pragma unroll
  for (int r = 0; r < 4; ++r){
    const float2 v = ((const float2*)ml)[(size_t)bh * 2048 + q0 + (l >> 4) * 4 + r];
    m_[r] = v.x; il[r] = 1.0f / v.y;
  }
  u16* Prow = P + ((size_t)h * QC + (q0 - qbase) + (l >> 4) * 4) * 2048;
  for (int kt = 0; kt < 32; ++kt){
    f32x4 s[4];
    #pragma unroll
    for (int n = 0; n < 4; ++n){
      s[n] = (f32x4){0.f, 0.f, 0.f, 0.f};
      const int krow = kt * 64 + n * 16 + (l & 15);
      const bf16x8 k0 = *(const bf16x8*)&Kh[(size_t)krow * 64 + (l >> 4) * 8];
      const bf16x8 k1 = *(const bf16x8*)&Kh[(size_t)krow * 64 + 32 + (l >> 4) * 8];
      s[n] = __builtin_amdgcn_mfma_f32_16x16x32_bf16(qa0, k0, s[n], 0, 0, 0);
      s[n] = __builtin_amdgcn_mfma_f32_16x16x32_bf16(qa1, k1, s[n], 0, 0, 0);
    }
    #pragma unroll
    for (int n = 0; n < 4; ++n){
      const int kc = kt * 64 + n * 16 + (l & 15);
      #pragma unroll
      for (int r = 0; r < 4; ++r){
        const float p = __expf(s[n][r] * 0.125f - m_[r]) * il[r];
        Prow[(size_t)r * 2048 + kc] = f2b(p);
      }
    }
  }
}

// ---------------- pass 2b: in-place talking-heads mix over h (16x16) ----------------
__global__ __launch_bounds__(256) void mix_k(u16* P, const float* __restrict__ Wm, int QC){
  const size_t c0 = ((size_t)blockIdx.x * 256 + threadIdx.x) * 4;
  const size_t stride = (size_t)QC * 2048;
  float acc[16][4];
  #pragma unroll
  for (int g = 0; g < 16; ++g){ acc[g][0] = 0.f; acc[g][1] = 0.f; acc[g][2] = 0.f; acc[g][3] = 0.f; }
  #pragma unroll
  for (int h = 0; h < 16; ++h){
    const ushort4 v = *(const ushort4*)&P[(size_t)h * stride + c0];
    const float f0 = b2f(v.x), f1 = b2f(v.y), f2c = b2f(v.z), f3 = b2f(v.w);
    #pragma unroll
    for (int g = 0; g < 16; ++g){
      const float wgt = Wm[g * 16 + h];
      acc[g][0] += wgt * f0; acc[g][1] += wgt * f1; acc[g][2] += wgt * f2c; acc[g][3] += wgt * f3;
    }
  }
  #pragma unroll
  for (int g = 0; g < 16; ++g){
    ushort4 o; o.x = f2b(acc[g][0]); o.y = f2b(acc[g][1]); o.z = f2b(acc[g][2]); o.w = f2b(acc[g][3]);
    *(ushort4*)&P[(size_t)g * stride + c0] = o;
  }
}

// ---------------- pass 2c: PV GEMM (M=QC, N=64, K=2048 per (b,g)) ----------------
__global__ __launch_bounds__(256) void pv_gemm(const u16* __restrict__ P, const u16* __restrict__ Vt,
    u16* __restrict__ AO, int b, int qbase, int QC)
{
  __shared__ __align__(16) u16 As[128 * 32];
  __shared__ __align__(16) u16 Bs[64 * 32];
  const int mt = blockIdx.x, g = blockIdx.y;
  const int tid = threadIdx.x, w = tid >> 6, l = tid & 63;
  const u16* Ab = P + ((size_t)g * QC + mt * 128) * 2048;
  const u16* Bb = Vt + (size_t)((b * 16 + g) * 64) * 2048;
  const int srow = w * 16 + (l >> 2), scol = (l & 3) * 8;
  f32x4 acc[2][4];
  #pragma unroll
  for (int m = 0; m < 2; ++m)
    #pragma unroll
    for (int n = 0; n < 4; ++n) acc[m][n] = (f32x4){0.f, 0.f, 0.f, 0.f};
  for (int kt = 0; kt < 64; ++kt){
    const int k0 = kt << 5;
    #pragma unroll
    for (int j = 0; j < 2; ++j)
      gll16(Ab + (size_t)(j * 64 + srow) * 2048 + k0 + scol, (char*)As + j * 4096 + w * 1024);
    gll16(Bb + (size_t)srow * 2048 + k0 + scol, (char*)Bs + w * 1024);
    __syncthreads();
    bf16x8 af[2], bfr[4];
    #pragma unroll
    for (int m = 0; m < 2; ++m) af[m]  = *(const bf16x8*)&As[(w * 32 + m * 16 + (l & 15)) * 32 + (l >> 4) * 8];
    #pragma unroll
    for (int n = 0; n < 4; ++n) bfr[n] = *(const bf16x8*)&Bs[(n * 16 + (l & 15)) * 32 + (l >> 4) * 8];
    #pragma unroll
    for (int m = 0; m < 2; ++m)
      #pragma unroll
      for (int n = 0; n < 4; ++n)
        acc[m][n] = __builtin_amdgcn_mfma_f32_16x16x32_bf16(af[m], bfr[n], acc[m][n], 0, 0, 0);
    __syncthreads();
  }
  #pragma unroll
  for (int m = 0; m < 2; ++m){
    #pragma unroll
    for (int n = 0; n < 4; ++n){
      #pragma unroll
      for (int r = 0; r < 4; ++r){
        const int qc = mt * 128 + w * 32 + m * 16 + (l >> 4) * 4 + r;
        const int d  = n * 16 + (l & 15);
        AO[((size_t)b * 2048 + qbase + qc) * 1024 + g * 64 + d] = f2b(acc[m][n][r]);
      }
    }
  }
}

// ---------------- V column sums (for bm term) ----------------
__global__ __launch_bounds__(256) void colsum_k(const u16* __restrict__ Vt, float* __restrict__ Vcs){
  const int rowd = blockIdx.x;                   // (b*16+h)*64 + d
  const u16* vr = Vt + (size_t)rowd * 2048;
  const int tid = threadIdx.x;
  const ushort4 a = *(const ushort4*)&vr[tid * 8];
  const ushort4 c = *(const ushort4*)&vr[tid * 8 + 4];
  float s = b2f(a.x) + b2f(a.y) + b2f(a.z) + b2f(a.w) + b2f(c.x) + b2f(c.y) + b2f(c.z) + b2f(c.w);
  #pragma unroll
  for (int off = 1; off < 64; off <<= 1) s += __shfl_xor(s, off);
  __shared__ float red[4];
  if ((tid & 63) == 0) red[tid >> 6] = s;
  __syncthreads();
  if (tid == 0) Vcs[rowd] = red[0] + red[1] + red[2] + red[3];
}

// ---------------- residual + bm*colsum + LayerNorm ----------------
__global__ __launch_bounds__(256) void ln_k(const u16* __restrict__ AO, const float* __restrict__ qin,
    const float* __restrict__ bm, const float* __restrict__ Vcs,
    const float* __restrict__ gam, const float* __restrict__ bet, u16* __restrict__ XBo)
{
  const int row = blockIdx.x, b = row >> 11, tid = threadIdx.x;
  const int c0 = tid * 4;
  const float4 qv = *(const float4*)&qin[(size_t)row * 1024 + c0];
  const ushort4 av = *(const ushort4*)&AO[(size_t)row * 1024 + c0];
  const int hh = c0 >> 6, dd = c0 & 63;
  const float bmv = bm[hh];
  const float* vc = Vcs + ((size_t)b * 16 + hh) * 64 + dd;
  float v[4];
  v[0] = b2f(av.x) + qv.x + bmv * vc[0];
  v[1] = b2f(av.y) + qv.y + bmv * vc[1];
  v[2] = b2f(av.z) + qv.z + bmv * vc[2];
  v[3] = b2f(av.w) + qv.w + bmv * vc[3];
  float s1 = v[0] + v[1] + v[2] + v[3];
  float s2 = v[0]*v[0] + v[1]*v[1] + v[2]*v[2] + v[3]*v[3];
  #pragma unroll
  for (int off = 1; off < 64; off <<= 1){ s1 += __shfl_xor(s1, off); s2 += __shfl_xor(s2, off); }
  __shared__ float r1[4], r2[4];
  if ((tid & 63) == 0){ r1[tid >> 6] = s1; r2[tid >> 6] = s2; }
  __syncthreads();
  const float t1 = r1[0] + r1[1] + r1[2] + r1[3];
  const float t2 = r2[0] + r2[1] + r2[2] + r2[3];
  const float mean = t1 * (1.0f / 1024.0f);
  const float var  = t2 * (1.0f / 1024.0f) - mean * mean;
  const float inv  = rsqrtf(var + 1e-5f);
  ushort4 o;
  o.x = f2b((v[0] - mean) * inv * gam[c0 + 0] + bet[c0 + 0]);
  o.y = f2b((v[1] - mean) * inv * gam[c0 + 1] + bet[c0 + 1]);
  o.z = f2b((v[2] - mean) * inv * gam[c0 + 2] + bet[c0 + 2]);
  o.w = f2b((v[3] - mean) * inv * gam[c0 + 3] + bet[c0 + 3]);
  *(ushort4*)&XBo[(size_t)row * 1024 + c0] = o;
}

extern "C" void kernel_launch(void* const* d_in, const int* in_sizes, int n_in,
                              void* d_out, int out_size, void* d_ws, size_t ws_size,
                              hipStream_t stream) {
  const float* q   = (const float*)d_in[0];
  const float* Wq  = (const float*)d_in[1];
  const float* bq  = (const float*)d_in[2];
  const float* Wk  = (const float*)d_in[3];
  const float* bk  = (const float*)d_in[4];
  const float* Wv  = (const float*)d_in[5];
  const float* bv  = (const float*)d_in[6];
  const float* Wm  = (const float*)d_in[7];
  const float* bm  = (const float*)d_in[8];
  const float* W1  = (const float*)d_in[9];
  const float* b1  = (const float*)d_in[10];
  const float* W2  = (const float*)d_in[11];
  const float* b2  = (const float*)d_in[12];
  const float* lng = (const float*)d_in[13];
  const float* lnb = (const float*)d_in[14];

  char* ws = (char*)d_ws;
  const size_t MB = 1u << 20;
  u16*  XB  = (u16*)(ws);             // 8 MB  bf16 x / xb
  u16*  WB  = (u16*)(ws + 8  * MB);   // 6 MB  packed weights (Wqkv, later W1|W2)
  u16*  Qb  = (u16*)(ws + 14 * MB);   // 8 MB  [b][h][q][64]
  u16*  Kb  = (u16*)(ws + 22 * MB);   // 8 MB  [b][h][k][64]   (reused as Hb for FFN)
  u16*  Vt  = (u16*)(ws + 30 * MB);   // 8 MB  [b][h][64][k]
  float* ml = (float*)(ws + 38 * MB); // 0.5 MB [b][h][q]{m,l}
  float* Vcs= (float*)(ws + 39 * MB); // 8 KB
  u16*  AO  = (u16*)(ws + 40 * MB);   // 8 MB  attention out bf16
  u16*  P   = (u16*)(ws + 48 * MB);   // 128/c MB: [h][QC][2048] bf16
  u16*  Hb  = Kb;

  const size_t avail = ws_size > 48 * MB ? ws_size - 48 * MB : 0;
  int c = 1;
  while (c < 16 && (size_t)16 * (2048 / c) * 2048 * 2 > avail) c <<= 1;
  const int QC = 2048 / c;

  pack_x <<<4096, 256, 0, stream>>>(q, XB);
  pack_wT<<<4096, 256, 0, stream>>>(Wq, WB);
  pack_wT<<<4096, 256, 0, stream>>>(Wk, WB + 1024 * 1024);
  pack_wT<<<4096, 256, 0, stream>>>(Wv, WB + 2 * 1024 * 1024);

  gemm_bt<0><<<dim3(32, 24), 256, 0, stream>>>(XB, WB, 1024, bq, bk, bv, Qb, Kb, Vt, nullptr, nullptr);

  pack_wT<<<4096, 256, 0, stream>>>(W1, WB);
  pack_wT<<<4096, 256, 0, stream>>>(W2, WB + 1024 * 1024);

  attn_ml <<<1024, 256, 0, stream>>>(Qb, Kb, ml);
  colsum_k<<<2048, 256, 0, stream>>>(Vt, Vcs);

  for (int b = 0; b < 2; ++b){
    for (int ch = 0; ch < c; ++ch){
      const int qbase = ch * QC;
      scores_p<<<dim3(16, QC / 64), 256, 0, stream>>>(Qb, Kb, ml, P, b, qbase, QC);
      mix_k   <<<QC * 2, 256, 0, stream>>>(P, Wm, QC);
      pv_gemm <<<dim3(QC / 128, 16), 256, 0, stream>>>(P, Vt, AO, b, qbase, QC);
    }
  }

  ln_k<<<4096, 256, 0, stream>>>(AO, q, bm, Vcs, lng, lnb, XB);

  gemm_bt<1><<<dim3(32, 8), 256, 0, stream>>>(XB, WB, 1024, b1, nullptr, nullptr, Hb, nullptr, nullptr, nullptr, nullptr);
  gemm_bt<3><<<dim3(32, 8), 256, 0, stream>>>(Hb, WB + 1024 * 1024, 1024, b2, nullptr, nullptr,
                                              nullptr, nullptr, nullptr, XB, (float*)d_out);
}

// Round 3
// 527.233 us; speedup vs baseline: 1.0866x; 1.0866x over previous
//
#include <hip/hip_runtime.h>
#include <math.h>

typedef unsigned short u16;
typedef unsigned int u32;
typedef __attribute__((ext_vector_type(8))) short bf16x8;
typedef __attribute__((ext_vector_type(4))) float f32x4;

__device__ __forceinline__ u16 f2b(float f){
  u32 u = __float_as_uint(f);
  u32 r = (u + 0x7FFFu + ((u >> 16) & 1u)) >> 16;
  return (u16)r;
}
__device__ __forceinline__ float b2f(u16 h){ return __uint_as_float(((u32)h) << 16); }

__device__ __forceinline__ void gll16(const void* g, void* l){
  __builtin_amdgcn_global_load_lds((const __attribute__((address_space(1))) void*)g,
                                   (__attribute__((address_space(3))) void*)l, 16, 0, 0);
}

// ---------------- pack kernels ----------------
__global__ __launch_bounds__(256) void pack_x(const float* __restrict__ in, u16* __restrict__ out){
  const int i = blockIdx.x * 256 + threadIdx.x;   // 4096*256 = 1,048,576 float4s exactly
  const float4 v = ((const float4*)in)[i];
  ushort4 o; o.x = f2b(v.x); o.y = f2b(v.y); o.z = f2b(v.z); o.w = f2b(v.w);
  ((ushort4*)out)[i] = o;
}

// coalesced tiled transpose: in f32 [1024 k][1024 n] -> out bf16 [1024 n][1024 k]
__global__ __launch_bounds__(256) void pack_wT(const float* __restrict__ in, u16* __restrict__ out){
  __shared__ u16 t[64][68];                       // stride 68 u16: ushort4 rows stay 8B-aligned
  const int k0 = (blockIdx.x & 15) * 64, n0 = (blockIdx.x >> 4) * 64;
  const int tx = threadIdx.x & 15, ty = threadIdx.x >> 4;
  #pragma unroll
  for (int j = 0; j < 4; ++j){
    const int r = ty + j * 16;                    // k-local
    const float4 v = *(const float4*)&in[(size_t)(k0 + r) * 1024 + n0 + tx * 4];
    t[tx*4+0][r] = f2b(v.x); t[tx*4+1][r] = f2b(v.y);
    t[tx*4+2][r] = f2b(v.z); t[tx*4+3][r] = f2b(v.w);
  }
  __syncthreads();
  #pragma unroll
  for (int j = 0; j < 4; ++j){
    const int c = ty + j * 16;                    // n-local
    *(ushort4*)&out[(size_t)(n0 + c) * 1024 + k0 + tx * 4] = *(const ushort4*)&t[c][tx * 4];
  }
}

// ---------------- 128x128 bf16 GEMM, B^T layout (m97 structure) ----------------
// EPI 0: QKV split. EPI 1: bias+gelu -> o0 (bf16). EPI 3: bias+residual -> fo (f32 d_out).
template<int EPI>
__global__ __launch_bounds__(256) void gemm_bt(
    const u16* __restrict__ A, const u16* __restrict__ Bt, int K,
    const float* __restrict__ bias0, const float* __restrict__ bias1, const float* __restrict__ bias2,
    u16* __restrict__ o0, u16* __restrict__ o1, u16* __restrict__ o2,
    const u16* __restrict__ res, float* __restrict__ fo)
{
  __shared__ __align__(16) u16 As[128 * 32];
  __shared__ __align__(16) u16 Bs[128 * 32];
  const int bm = blockIdx.x, bn = blockIdx.y;
  const int tid = threadIdx.x, w = tid >> 6, l = tid & 63;
  const int wm = (w >> 1) * 64, wn = (w & 1) * 64;
  const u16* Ab = A + (size_t)bm * 128 * K;
  const u16* Bb = Bt + (size_t)bn * 128 * K;
  const int srow = w * 16 + (l >> 2);
  const int scol = (l & 3) * 8;
  f32x4 acc[4][4];
  #pragma unroll
  for (int m = 0; m < 4; ++m)
    #pragma unroll
    for (int n = 0; n < 4; ++n) acc[m][n] = (f32x4){0.f, 0.f, 0.f, 0.f};
  const int nk = K >> 5;
  for (int kt = 0; kt < nk; ++kt){
    const int k0 = kt << 5;
    #pragma unroll
    for (int j = 0; j < 2; ++j){
      gll16(Ab + (size_t)(j * 64 + srow) * K + (k0 + scol), (char*)As + j * 4096 + w * 1024);
      gll16(Bb + (size_t)(j * 64 + srow) * K + (k0 + scol), (char*)Bs + j * 4096 + w * 1024);
    }
    __syncthreads();
    bf16x8 af[4], bfr[4];
    #pragma unroll
    for (int m = 0; m < 4; ++m) af[m]  = *(const bf16x8*)&As[(wm + m * 16 + (l & 15)) * 32 + (l >> 4) * 8];
    #pragma unroll
    for (int n = 0; n < 4; ++n) bfr[n] = *(const bf16x8*)&Bs[(wn + n * 16 + (l & 15)) * 32 + (l >> 4) * 8];
    #pragma unroll
    for (int m = 0; m < 4; ++m)
      #pragma unroll
      for (int n = 0; n < 4; ++n)
        acc[m][n] = __builtin_amdgcn_mfma_f32_16x16x32_bf16(af[m], bfr[n], acc[m][n], 0, 0, 0);
    __syncthreads();
  }
  #pragma unroll
  for (int m = 0; m < 4; ++m){
    #pragma unroll
    for (int n = 0; n < 4; ++n){
      const int row0 = bm * 128 + wm + m * 16 + ((l >> 4) << 2);
      const int col  = bn * 128 + wn + n * 16 + (l & 15);
      if (EPI == 0){
        const int sec = col >> 10, cw = col & 1023, hh = cw >> 6, d = cw & 63;
        const float bias = (sec == 0 ? bias0 : (sec == 1 ? bias1 : bias2))[cw];
        #pragma unroll
        for (int r = 0; r < 4; ++r){
          const int rr = row0 + r, bi = rr >> 11, seq = rr & 2047;
          const float v = acc[m][n][r] + bias;
          if (sec == 0)      o0[(((size_t)bi * 16 + hh) * 2048 + seq) * 64 + d] = f2b(v);
          else if (sec == 1) o1[(((size_t)bi * 16 + hh) * 2048 + seq) * 64 + d] = f2b(v);
          else               o2[(((size_t)bi * 16 + hh) * 64 + d) * 2048 + seq] = f2b(v);
        }
      } else if (EPI == 1){
        const float bias = bias0[col];
        #pragma unroll
        for (int r = 0; r < 4; ++r){
          const float v = acc[m][n][r] + bias;
          const float gv = 0.5f * v * (1.0f + erff(v * 0.70710678118654752f));
          o0[(size_t)(row0 + r) * 1024 + col] = f2b(gv);
        }
      } else {  // EPI == 3: bias + bf16 residual -> float32 output
        const float bias = bias0[col];
        #pragma unroll
        for (int r = 0; r < 4; ++r){
          const float v = acc[m][n][r] + bias + b2f(res[(size_t)(row0 + r) * 1024 + col]);
          fo[(size_t)(row0 + r) * 1024 + col] = v;
        }
      }
    }
  }
}

// ---------------- attention pass 1: per-row (m, l) via swapped MFMA, lane-local stats ----------------
__global__ __launch_bounds__(256) void attn_ml(const u16* __restrict__ Qb, const u16* __restrict__ Kb,
                                               float* __restrict__ ml){
  const int qt = blockIdx.x & 31, bh = blockIdx.x >> 5;
  const int tid = threadIdx.x, w = tid >> 6, l = tid & 63;
  const u16* Qh = Qb + (size_t)bh * (2048 * 64);
  const u16* Kh = Kb + (size_t)bh * (2048 * 64);
  const int q0 = qt * 64 + w * 16;
  // Q as B-operand: rows q = l&15
  const bf16x8 qb0 = *(const bf16x8*)&Qh[(size_t)(q0 + (l & 15)) * 64 + (l >> 4) * 8];
  const bf16x8 qb1 = *(const bf16x8*)&Qh[(size_t)(q0 + (l & 15)) * 64 + 32 + (l >> 4) * 8];
  float m = -1e30f, ls = 0.f;
  for (int kt = 0; kt < 128; ++kt){
    const int krow = kt * 16 + (l & 15);
    const bf16x8 ka0 = *(const bf16x8*)&Kh[(size_t)krow * 64 + (l >> 4) * 8];
    const bf16x8 ka1 = *(const bf16x8*)&Kh[(size_t)krow * 64 + 32 + (l >> 4) * 8];
    f32x4 s = (f32x4){0.f, 0.f, 0.f, 0.f};
    s = __builtin_amdgcn_mfma_f32_16x16x32_bf16(ka0, qb0, s, 0, 0, 0);
    s = __builtin_amdgcn_mfma_f32_16x16x32_bf16(ka1, qb1, s, 0, 0, 0);
    const float v0 = s[0] * 0.125f, v1 = s[1] * 0.125f, v2 = s[2] * 0.125f, v3 = s[3] * 0.125f;
    const float mt = fmaxf(fmaxf(v0, v1), fmaxf(v2, v3));
    const float mn = fmaxf(m, mt);
    ls = ls * __expf(m - mn) + __expf(v0 - mn) + __expf(v1 - mn) + __expf(v2 - mn) + __expf(v3 - mn);
    m = mn;
  }
  // combine across the 4 lane groups holding the same q (= l&15)
  #pragma unroll
  for (int off = 16; off < 64; off <<= 1){
    const float mo = __shfl_xor(m, off), lo = __shfl_xor(ls, off);
    const float mn = fmaxf(m, mo);
    ls = ls * __expf(m - mn) + lo * __expf(mo - mn);
    m = mn;
  }
  if (l < 16){
    float2 st; st.x = m; st.y = ls;
    ((float2*)ml)[(size_t)bh * 2048 + q0 + l] = st;
  }
}

// ---------------- fused pass 2: scores + talking-heads mix (MFMA over h) + PV ----------------
// block = (qt of 16 q rows, b). 16 waves: QK phase wave = (h-pair, k-half); mix chunk q = w; PV g = w.
__global__ __launch_bounds__(1024) void attn_fused(
    const u16* __restrict__ Qb, const u16* __restrict__ Kb, const u16* __restrict__ Vt,
    const float* __restrict__ ml, const float* __restrict__ Wm, u16* __restrict__ AO)
{
  __shared__ __align__(16) u16 P2[16 * 32 * 40];   // [q][k][h] h-dim padded to 40 (h 16..31 zeroed)
  __shared__ __align__(16) u16 A2[16 * 16 * 40];   // [g][q][k] k-dim padded to 40, k XOR ((g&7)<<2)
  const int qt = blockIdx.x, b = blockIdx.y;
  const int tid = threadIdx.x, w = tid >> 6, l = tid & 63;
  const int q0 = qt * 16;
  const int h0 = (w & 7) * 2;        // QK phase: heads h0, h0+1
  const int khw = w >> 3;            // QK phase: k-half
  const u16* Qh0 = Qb + (size_t)(b * 16 + h0) * (2048 * 64);
  const u16* Qh1 = Qh0 + (size_t)2048 * 64;
  const u16* Kh0 = Kb + (size_t)(b * 16 + h0) * (2048 * 64);
  const u16* Kh1 = Kh0 + (size_t)2048 * 64;
  const u16* Vg  = Vt + (size_t)(b * 16 + w) * (64 * 2048);   // PV: g = w

  // zero the h=16..31 slots of P2 once (mix MFMA contracts K=32 with zero padding)
  {
    const int qk = tid >> 1, o = tid & 1;
    ((uint4*)P2)[qk * 5 + 2 + o] = (uint4){0u, 0u, 0u, 0u};
  }

  // Q fragments (A-operand rows q = l&15)
  const bf16x8 qa0 = *(const bf16x8*)&Qh0[(size_t)(q0 + (l & 15)) * 64 + (l >> 4) * 8];
  const bf16x8 qa1 = *(const bf16x8*)&Qh0[(size_t)(q0 + (l & 15)) * 64 + 32 + (l >> 4) * 8];
  const bf16x8 qa2 = *(const bf16x8*)&Qh1[(size_t)(q0 + (l & 15)) * 64 + (l >> 4) * 8];
  const bf16x8 qa3 = *(const bf16x8*)&Qh1[(size_t)(q0 + (l & 15)) * 64 + 32 + (l >> 4) * 8];

  // per-lane softmax stats for rows q = q0 + (l>>4)*4 + r, heads h0/h0+1
  float m_[2][4], il_[2][4];
  #pragma unroll
  for (int hp = 0; hp < 2; ++hp)
    #pragma unroll
    for (int r = 0; r < 4; ++r){
      const float2 v = ((const float2*)ml)[(size_t)(b * 16 + h0 + hp) * 2048 + q0 + (l >> 4) * 4 + r];
      m_[hp][r] = v.x; il_[hp][r] = 1.0f / v.y;
    }

  // Wm fragment for mix MFMA (B-operand rows g = l&15, contraction h = (l>>4)*8+i, zero for h>=16)
  bf16x8 wmf;
  #pragma unroll
  for (int i = 0; i < 8; ++i){
    const int hh = (l >> 4) * 8 + i;
    wmf[i] = (hh < 16) ? (short)f2b(Wm[(l & 15) * 16 + hh]) : (short)0;
  }

  f32x4 opv[4];
  #pragma unroll
  for (int nd = 0; nd < 4; ++nd) opv[nd] = (f32x4){0.f, 0.f, 0.f, 0.f};

  const int swzw = (w & 7) << 2;

  for (int kt = 0; kt < 64; ++kt){
    const int k0 = kt * 32;
    // ---- phase A: QK^T (h-pair, k-half) + softmax + packed P write ----
    {
      const int krow = k0 + khw * 16 + (l & 15);
      const bf16x8 kb00 = *(const bf16x8*)&Kh0[(size_t)krow * 64 + (l >> 4) * 8];
      const bf16x8 kb01 = *(const bf16x8*)&Kh0[(size_t)krow * 64 + 32 + (l >> 4) * 8];
      const bf16x8 kb10 = *(const bf16x8*)&Kh1[(size_t)krow * 64 + (l >> 4) * 8];
      const bf16x8 kb11 = *(const bf16x8*)&Kh1[(size_t)krow * 64 + 32 + (l >> 4) * 8];
      f32x4 s0 = (f32x4){0.f, 0.f, 0.f, 0.f}, s1 = (f32x4){0.f, 0.f, 0.f, 0.f};
      s0 = __builtin_amdgcn_mfma_f32_16x16x32_bf16(qa0, kb00, s0, 0, 0, 0);
      s0 = __builtin_amdgcn_mfma_f32_16x16x32_bf16(qa1, kb01, s0, 0, 0, 0);
      s1 = __builtin_amdgcn_mfma_f32_16x16x32_bf16(qa2, kb10, s1, 0, 0, 0);
      s1 = __builtin_amdgcn_mfma_f32_16x16x32_bf16(qa3, kb11, s1, 0, 0, 0);
      const int k_loc = khw * 16 + (l & 15);
      #pragma unroll
      for (int r = 0; r < 4; ++r){
        const float p0 = __expf(s0[r] * 0.125f - m_[0][r]) * il_[0][r];
        const float p1 = __expf(s1[r] * 0.125f - m_[1][r]) * il_[1][r];
        const u32 pk = (u32)f2b(p0) | ((u32)f2b(p1) << 16);
        const int q_loc = (l >> 4) * 4 + r;
        *(u32*)&P2[(q_loc * 32 + k_loc) * 40 + h0] = pk;
      }
    }
    __syncthreads();   // P2 ready (and previous A2 fully consumed)
    // ---- phase B: talking-heads mix via MFMA over h; write A2 ----
    #pragma unroll
    for (int kh = 0; kh < 2; ++kh){
      const bf16x8 pfrag = *(const bf16x8*)&P2[(w * 32 + kh * 16 + (l & 15)) * 40 + (l >> 4) * 8];
      f32x4 a2 = (f32x4){0.f, 0.f, 0.f, 0.f};
      a2 = __builtin_amdgcn_mfma_f32_16x16x32_bf16(pfrag, wmf, a2, 0, 0, 0);
      // lane holds g = l&15, k-local = kh*16 + (l>>4)*4 + r (4 consecutive)
      const u32 lo = (u32)f2b(a2[0]) | ((u32)f2b(a2[1]) << 16);
      const u32 hi = (u32)f2b(a2[2]) | ((u32)f2b(a2[3]) << 16);
      const int g = l & 15;
      const int kb = (kh * 16 + (l >> 4) * 4) ^ ((g & 7) << 2);
      uint2 pkd; pkd.x = lo; pkd.y = hi;
      *(uint2*)&A2[(g * 16 + w) * 40 + kb] = pkd;
    }
    __syncthreads();   // A2 ready
    // ---- phase C: PV MFMA for g = w ----
    {
      const int base = (w * 16 + (l & 15)) * 40;
      const uint2 a0 = *(const uint2*)&A2[base + (((l >> 4) * 8) ^ swzw)];
      const uint2 a1 = *(const uint2*)&A2[base + ((((l >> 4) * 8) + 4) ^ swzw)];
      union { uint2 u[2]; bf16x8 v; } cv;
      cv.u[0] = a0; cv.u[1] = a1;
      #pragma unroll
      for (int nd = 0; nd < 4; ++nd){
        const bf16x8 vb = *(const bf16x8*)&Vg[(size_t)(nd * 16 + (l & 15)) * 2048 + k0 + (l >> 4) * 8];
        opv[nd] = __builtin_amdgcn_mfma_f32_16x16x32_bf16(cv.v, vb, opv[nd], 0, 0, 0);
      }
    }
  }
  // epilogue: rows q = q0 + (l>>4)*4 + r, col d = nd*16 + (l&15), head g = w
  #pragma unroll
  for (int nd = 0; nd < 4; ++nd)
    #pragma unroll
    for (int r = 0; r < 4; ++r)
      AO[((size_t)b * 2048 + q0 + (l >> 4) * 4 + r) * 1024 + w * 64 + nd * 16 + (l & 15)] = f2b(opv[nd][r]);
}

// ---------------- V column sums (for bm term) ----------------
__global__ __launch_bounds__(256) void colsum_k(const u16* __restrict__ Vt, float* __restrict__ Vcs){
  const int rowd = blockIdx.x;                   // (b*16+h)*64 + d
  const u16* vr = Vt + (size_t)rowd * 2048;
  const int tid = threadIdx.x;
  const ushort4 a = *(const ushort4*)&vr[tid * 8];
  const ushort4 c = *(const ushort4*)&vr[tid * 8 + 4];
  float s = b2f(a.x) + b2f(a.y) + b2f(a.z) + b2f(a.w) + b2f(c.x) + b2f(c.y) + b2f(c.z) + b2f(c.w);
  #pragma unroll
  for (int off = 1; off < 64; off <<= 1) s += __shfl_xor(s, off);
  __shared__ float red[4];
  if ((tid & 63) == 0) red[tid >> 6] = s;
  __syncthreads();
  if (tid == 0) Vcs[rowd] = red[0] + red[1] + red[2] + red[3];
}

// ---------------- residual + bm*colsum + LayerNorm ----------------
__global__ __launch_bounds__(256) void ln_k(const u16* __restrict__ AO, const float* __restrict__ qin,
    const float* __restrict__ bm, const float* __restrict__ Vcs,
    const float* __restrict__ gam, const float* __restrict__ bet, u16* __restrict__ XBo)
{
  const int row = blockIdx.x, b = row >> 11, tid = threadIdx.x;
  const int c0 = tid * 4;
  const float4 qv = *(const float4*)&qin[(size_t)row * 1024 + c0];
  const ushort4 av = *(const ushort4*)&AO[(size_t)row * 1024 + c0];
  const int hh = c0 >> 6, dd = c0 & 63;
  const float bmv = bm[hh];
  const float* vc = Vcs + ((size_t)b * 16 + hh) * 64 + dd;
  float v[4];
  v[0] = b2f(av.x) + qv.x + bmv * vc[0];
  v[1] = b2f(av.y) + qv.y + bmv * vc[1];
  v[2] = b2f(av.z) + qv.z + bmv * vc[2];
  v[3] = b2f(av.w) + qv.w + bmv * vc[3];
  float s1 = v[0] + v[1] + v[2] + v[3];
  float s2 = v[0]*v[0] + v[1]*v[1] + v[2]*v[2] + v[3]*v[3];
  #pragma unroll
  for (int off = 1; off < 64; off <<= 1){ s1 += __shfl_xor(s1, off); s2 += __shfl_xor(s2, off); }
  __shared__ float r1[4], r2[4];
  if ((tid & 63) == 0){ r1[tid >> 6] = s1; r2[tid >> 6] = s2; }
  __syncthreads();
  const float t1 = r1[0] + r1[1] + r1[2] + r1[3];
  const float t2 = r2[0] + r2[1] + r2[2] + r2[3];
  const float mean = t1 * (1.0f / 1024.0f);
  const float var  = t2 * (1.0f / 1024.0f) - mean * mean;
  const float inv  = rsqrtf(var + 1e-5f);
  ushort4 o;
  o.x = f2b((v[0] - mean) * inv * gam[c0 + 0] + bet[c0 + 0]);
  o.y = f2b((v[1] - mean) * inv * gam[c0 + 1] + bet[c0 + 1]);
  o.z = f2b((v[2] - mean) * inv * gam[c0 + 2] + bet[c0 + 2]);
  o.w = f2b((v[3] - mean) * inv * gam[c0 + 3] + bet[c0 + 3]);
  *(ushort4*)&XBo[(size_t)row * 1024 + c0] = o;
}

extern "C" void kernel_launch(void* const* d_in, const int* in_sizes, int n_in,
                              void* d_out, int out_size, void* d_ws, size_t ws_size,
                              hipStream_t stream) {
  const float* q   = (const float*)d_in[0];
  const float* Wq  = (const float*)d_in[1];
  const float* bq  = (const float*)d_in[2];
  const float* Wk  = (const float*)d_in[3];
  const float* bk  = (const float*)d_in[4];
  const float* Wv  = (const float*)d_in[5];
  const float* bv  = (const float*)d_in[6];
  const float* Wm  = (const float*)d_in[7];
  const float* bm  = (const float*)d_in[8];
  const float* W1  = (const float*)d_in[9];
  const float* b1  = (const float*)d_in[10];
  const float* W2  = (const float*)d_in[11];
  const float* b2  = (const float*)d_in[12];
  const float* lng = (const float*)d_in[13];
  const float* lnb = (const float*)d_in[14];

  char* ws = (char*)d_ws;
  const size_t MB = 1u << 20;
  u16*  XB  = (u16*)(ws);             // 8 MB  bf16 x / xb
  u16*  WB  = (u16*)(ws + 8  * MB);   // 6 MB  packed weights (Wqkv, later W1|W2)
  u16*  Qb  = (u16*)(ws + 14 * MB);   // 8 MB  [b][h][q][64]
  u16*  Kb  = (u16*)(ws + 22 * MB);   // 8 MB  [b][h][k][64]   (reused as Hb for FFN)
  u16*  Vt  = (u16*)(ws + 30 * MB);   // 8 MB  [b][h][64][k]
  float* ml = (float*)(ws + 38 * MB); // 0.5 MB [b][h][q]{m,l}
  float* Vcs= (float*)(ws + 39 * MB); // 8 KB
  u16*  AO  = (u16*)(ws + 40 * MB);   // 8 MB  attention out bf16
  u16*  Hb  = Kb;

  pack_x <<<4096, 256, 0, stream>>>(q, XB);
  pack_wT<<<256, 256, 0, stream>>>(Wq, WB);
  pack_wT<<<256, 256, 0, stream>>>(Wk, WB + 1024 * 1024);
  pack_wT<<<256, 256, 0, stream>>>(Wv, WB + 2 * 1024 * 1024);

  gemm_bt<0><<<dim3(32, 24), 256, 0, stream>>>(XB, WB, 1024, bq, bk, bv, Qb, Kb, Vt, nullptr, nullptr);

  pack_wT<<<256, 256, 0, stream>>>(W1, WB);
  pack_wT<<<256, 256, 0, stream>>>(W2, WB + 1024 * 1024);

  attn_ml <<<1024, 256, 0, stream>>>(Qb, Kb, ml);
  colsum_k<<<2048, 256, 0, stream>>>(Vt, Vcs);

  attn_fused<<<dim3(128, 2), 1024, 0, stream>>>(Qb, Kb, Vt, ml, Wm, AO);

  ln_k<<<4096, 256, 0, stream>>>(AO, q, bm, Vcs, lng, lnb, XB);

  gemm_bt<1><<<dim3(32, 8), 256, 0, stream>>>(XB, WB, 1024, b1, nullptr, nullptr, Hb, nullptr, nullptr, nullptr, nullptr);
  gemm_bt<3><<<dim3(32, 8), 256, 0, stream>>>(Hb, WB + 1024 * 1024, 1024, b2, nullptr, nullptr,
                                              nullptr, nullptr, nullptr, XB, (float*)d_out);
}